// Round 2
// baseline (111321.777 us; speedup 1.0000x reference)
//
#include <hip/hip_runtime.h>
#include <hip/hip_bf16.h>
#include <hip/hip_cooperative_groups.h>
#include <math.h>

namespace cg = cooperative_groups;

#define B_  64
#define T_  512
#define I_  512
#define H_  1024
#define G4_ 4096
#define O_  512
#define TC_ 128            // time chunk
#define NCH (T_ / TC_)     // 4
#define NWG 256            // cooperative grid = 1 WG per CU

typedef short  s16x8 __attribute__((ext_vector_type(8)));
typedef float  fx4   __attribute__((ext_vector_type(4)));
typedef float  fx8   __attribute__((ext_vector_type(8)));
typedef unsigned short u16;
typedef u16    u16x4 __attribute__((ext_vector_type(4)));

__device__ __forceinline__ u16 f2bf(float f){
  unsigned u = __float_as_uint(f);
  unsigned r = u + 0x7fffu + ((u >> 16) & 1u);   // RNE
  return (u16)(r >> 16);
}
__device__ __forceinline__ float bf2f(u16 s){ return __uint_as_float(((unsigned)s) << 16); }
__device__ __forceinline__ float sigm(float x){ return 1.0f / (1.0f + __expf(-x)); }
__device__ __forceinline__ float tanh_(float x){
  float ax = fabsf(x);
  float e  = __expf(2.0f * ax);
  float r  = 1.0f - 2.0f / (e + 1.0f);
  return copysignf(r, x);
}
__device__ __forceinline__ fx4 mfma(s16x8 a, s16x8 b, fx4 c){
  return __builtin_amdgcn_mfma_f32_16x16x32_bf16(a, b, c, 0, 0, 0);
}

// ---------------- prep kernels ----------------
__global__ void cvt_hilo(const float* __restrict__ src, u16* __restrict__ hi,
                         u16* __restrict__ lo, int n4){
  int i      = blockIdx.x * blockDim.x + threadIdx.x;
  int stride = gridDim.x * blockDim.x;
  for (; i < n4; i += stride){
    fx4 v = ((const fx4*)src)[i];
    u16x4 h, l;
    #pragma unroll
    for (int k = 0; k < 4; ++k){
      u16 hh = f2bf(v[k]);
      h[k] = hh;
      l[k] = f2bf(v[k] - bf2f(hh));
    }
    ((u16x4*)hi)[i] = h;
    ((u16x4*)lo)[i] = l;
  }
}

__global__ void vadd(const float* __restrict__ a, const float* __restrict__ b,
                     float* __restrict__ o, int n){
  int i = blockIdx.x * blockDim.x + threadIdx.x;
  if (i < n) o[i] = a[i] + b[i];
}

// ---------------- GEMM (split-bf16, 64x64 tile, streaming) ----------------
// Computes out[r, n] = sum_k A[r, k] * Bmat[n, k] + bias[n]
// M = 64 * TC_ rows; row r maps to (b = r/TC_, tl = r%TC_).
// AMODE 0: A = fp32 tensor x, addressed [b][c0+tl][KD]; AMODE 1: A = hi/lo pair [r][KD].
// OUT_BT false: out[r*N + n]  (chunk-local [b][tl][N]); true: out[(b*T_+c0+tl)*N + n].
template<int KD, int AMODE, bool OUT_BT>
__global__ __launch_bounds__(256)
void gemm3(const float* __restrict__ Af,
           const u16* __restrict__ Ah, const u16* __restrict__ Al,
           const u16* __restrict__ Bh, const u16* __restrict__ Bl,
           const float* __restrict__ bias,
           float* __restrict__ out, int N, int c0)
{
  const int lane = threadIdx.x & 63;
  const int wv   = threadIdx.x >> 6;
  const int l15  = lane & 15;
  const int lhi  = lane >> 4;
  const int koff = lhi * 8;
  const int mb   = blockIdx.x * 64 + wv * 16;
  const int nb   = blockIdx.y * 64;
  const int arow = mb + l15;

  fx4 acc[4] = {};
  for (int kt = 0; kt < KD / 32; ++kt){
    const int kb = kt * 32 + koff;
    s16x8 ah, al;
    if (AMODE == 0){
      const int b  = arow / TC_;
      const int tl = arow % TC_;
      const float* p = Af + ((size_t)b * T_ + c0 + tl) * KD + kb;
      fx8 v = *reinterpret_cast<const fx8*>(p);
      #pragma unroll
      for (int i = 0; i < 8; ++i){
        u16 h = f2bf(v[i]);
        ah[i] = (short)h;
        al[i] = (short)f2bf(v[i] - bf2f(h));
      }
    } else {
      const size_t ao = (size_t)arow * KD + kb;
      ah = *reinterpret_cast<const s16x8*>(Ah + ao);
      al = *reinterpret_cast<const s16x8*>(Al + ao);
    }
    #pragma unroll
    for (int c = 0; c < 4; ++c){
      const size_t wo = (size_t)(nb + c * 16 + l15) * KD + kb;
      s16x8 bh = *reinterpret_cast<const s16x8*>(Bh + wo);
      s16x8 bl = *reinterpret_cast<const s16x8*>(Bl + wo);
      acc[c] = mfma(ah, bh, acc[c]);
      acc[c] = mfma(ah, bl, acc[c]);
      acc[c] = mfma(al, bh, acc[c]);
    }
  }
  #pragma unroll
  for (int c = 0; c < 4; ++c){
    const int n = nb + c * 16 + l15;
    const float bv = bias[n];
    #pragma unroll
    for (int r = 0; r < 4; ++r){
      const int m = mb + lhi * 4 + r;      // row index
      float v = acc[c][r] + bv;
      if (OUT_BT){
        const int b  = m / TC_;
        const int tl = m % TC_;
        out[((size_t)b * T_ + c0 + tl) * (size_t)N + n] = v;
      } else {
        out[(size_t)m * (size_t)N + n] = v;
      }
    }
  }
}

// ---------------- persistent cooperative LSTM chunk ----------------
// 256 WGs x 512 threads. WG owns 4 hidden units (16 gate-cols). 8 waves K-split
// the recurrent K=1024 (128 each); Whh fragments register-resident for the whole
// chunk. One grid.sync per timestep; h state double-buffered (hi/lo bf16).
__global__ __launch_bounds__(512, 2)
void lstm_chunk(const u16* __restrict__ Whh_hi, const u16* __restrict__ Whh_lo, // [4096,1024]
                const float* __restrict__ xp,   // [B][TC_][4096] fp32, bias included
                float* __restrict__ cst,        // [H][B] layout: j*B_ + m
                u16* __restrict__ h0h, u16* __restrict__ h0l,   // state parity 0 [B][H]
                u16* __restrict__ h1h, u16* __restrict__ h1l,   // state parity 1 [B][H]
                u16* __restrict__ hah, u16* __restrict__ hal)   // archive [B][TC_][H]
{
  cg::grid_group grid = cg::this_grid();
  __shared__ float red[16 * 8 * 64];        // [c][w][m]

  const int tid  = threadIdx.x;
  const int lane = tid & 63;
  const int wv   = tid >> 6;                // 0..7
  const int l15  = lane & 15;
  const int lhi  = lane >> 4;
  const int koff = lhi * 8;
  const int jb4  = blockIdx.x * 4;          // 4 hidden units per WG
  // B-col c = l15 -> gate g = c>>2, unit j = jb4 + (c&3); W row = g*H + j
  const int wrow = (l15 >> 2) * H_ + jb4 + (l15 & 3);

  // preload Whh fragments for this wave's 4 k-steps (k in [wv*128, wv*128+128))
  s16x8 wfh[4], wfl[4];
  #pragma unroll
  for (int s = 0; s < 4; ++s){
    const size_t wo = (size_t)wrow * H_ + wv * 128 + s * 32 + koff;
    wfh[s] = *reinterpret_cast<const s16x8*>(Whh_hi + wo);
    wfl[s] = *reinterpret_cast<const s16x8*>(Whh_lo + wo);
  }

  const int em = tid & 63;                  // epilogue: batch row
  const int eu = (tid >> 6) & 3;            // epilogue: unit 0..3 (tid<256 active)
  const int ej = jb4 + eu;

  for (int t = 0; t < TC_; ++t){
    const u16* rh = (t & 1) ? h1h : h0h;
    const u16* rl = (t & 1) ? h1l : h0l;
    u16* nh = (t & 1) ? h0h : h1h;
    u16* nl = (t & 1) ? h0l : h1l;

    fx4 acc[4] = {};
    #pragma unroll
    for (int s = 0; s < 4; ++s){
      const int kb = wv * 128 + s * 32 + koff;
      #pragma unroll
      for (int mt = 0; mt < 4; ++mt){
        const size_t ho = (size_t)(mt * 16 + l15) * H_ + kb;
        s16x8 ah = *reinterpret_cast<const s16x8*>(rh + ho);
        s16x8 al = *reinterpret_cast<const s16x8*>(rl + ho);
        acc[mt] = mfma(ah, wfh[s], acc[mt]);
        acc[mt] = mfma(ah, wfl[s], acc[mt]);
        acc[mt] = mfma(al, wfh[s], acc[mt]);
      }
    }
    // partials -> LDS: red[c][w][m]; D layout col=l15, row m = mt*16 + lhi*4 + r
    #pragma unroll
    for (int mt = 0; mt < 4; ++mt)
      #pragma unroll
      for (int r = 0; r < 4; ++r)
        red[(l15 * 8 + wv) * 64 + mt * 16 + lhi * 4 + r] = acc[mt][r];
    __syncthreads();

    if (tid < 256){
      float g[4];
      #pragma unroll
      for (int gi = 0; gi < 4; ++gi){
        const int c = gi * 4 + eu;
        float s = 0.0f;
        #pragma unroll
        for (int w = 0; w < 8; ++w) s += red[(c * 8 + w) * 64 + em];
        g[gi] = s + xp[((size_t)em * TC_ + t) * G4_ + gi * H_ + ej];
      }
      float iv = sigm (g[0]);
      float fv = sigm (g[1]);
      float gv = tanh_(g[2]);
      float ov = sigm (g[3]);
      const int ci = ej * B_ + em;          // c-state [j][m], coalesced
      float cn = fv * cst[ci] + iv * gv;
      float hv = ov * tanh_(cn);
      cst[ci] = cn;
      u16 hh = f2bf(hv);
      u16 hl = f2bf(hv - bf2f(hh));
      const int hi_ = em * H_ + ej;         // h state [m][k] for MFMA A-frags
      nh[hi_] = hh;
      nl[hi_] = hl;
      const size_t ai = ((size_t)em * TC_ + t) * H_ + ej;
      hah[ai] = hh;
      hal[ai] = hl;
    }
    __threadfence();
    grid.sync();
  }
}

// ---------------- host launch ----------------
extern "C" void kernel_launch(void* const* d_in, const int* in_sizes, int n_in,
                              void* d_out, int out_size, void* d_ws, size_t ws_size,
                              hipStream_t stream)
{
  const float* x    = (const float*)d_in[0];
  const float* Wih1 = (const float*)d_in[1];
  const float* Whh1 = (const float*)d_in[2];
  const float* bih1 = (const float*)d_in[3];
  const float* bhh1 = (const float*)d_in[4];
  const float* Wih2 = (const float*)d_in[5];
  const float* Whh2 = (const float*)d_in[6];
  const float* bih2 = (const float*)d_in[7];
  const float* bhh2 = (const float*)d_in[8];
  const float* fcW  = (const float*)d_in[9];
  const float* fcb  = (const float*)d_in[10];
  float* out = (float*)d_out;
  (void)in_sizes; (void)n_in; (void)out_size; (void)ws_size;

  char* base = (char*)d_ws;
  size_t off = 0;
  auto alloc = [&](size_t bytes) -> void* {
    void* p = base + off;
    off = (off + bytes + 255) & ~(size_t)255;
    return p;
  };
  u16* Wih1_hi = (u16*)alloc((size_t)G4_ * I_ * 2);
  u16* Wih1_lo = (u16*)alloc((size_t)G4_ * I_ * 2);
  u16* Whh1_hi = (u16*)alloc((size_t)G4_ * H_ * 2);
  u16* Whh1_lo = (u16*)alloc((size_t)G4_ * H_ * 2);
  u16* Wih2_hi = (u16*)alloc((size_t)G4_ * H_ * 2);
  u16* Wih2_lo = (u16*)alloc((size_t)G4_ * H_ * 2);
  u16* Whh2_hi = (u16*)alloc((size_t)G4_ * H_ * 2);
  u16* Whh2_lo = (u16*)alloc((size_t)G4_ * H_ * 2);
  u16* fcW_hi  = (u16*)alloc((size_t)O_ * H_ * 2);
  u16* fcW_lo  = (u16*)alloc((size_t)O_ * H_ * 2);
  float* bsum1 = (float*)alloc((size_t)G4_ * 4);
  float* bsum2 = (float*)alloc((size_t)G4_ * 4);
  float* cst1  = (float*)alloc((size_t)B_ * H_ * 4);
  float* cst2  = (float*)alloc((size_t)B_ * H_ * 4);
  u16* h1b0h = (u16*)alloc((size_t)B_ * H_ * 2);
  u16* h1b0l = (u16*)alloc((size_t)B_ * H_ * 2);
  u16* h1b1h = (u16*)alloc((size_t)B_ * H_ * 2);
  u16* h1b1l = (u16*)alloc((size_t)B_ * H_ * 2);
  u16* h2b0h = (u16*)alloc((size_t)B_ * H_ * 2);
  u16* h2b0l = (u16*)alloc((size_t)B_ * H_ * 2);
  u16* h2b1h = (u16*)alloc((size_t)B_ * H_ * 2);
  u16* h2b1l = (u16*)alloc((size_t)B_ * H_ * 2);
  u16* h1s_hi = (u16*)alloc((size_t)B_ * TC_ * H_ * 2);   // chunk archive L1
  u16* h1s_lo = (u16*)alloc((size_t)B_ * TC_ * H_ * 2);
  u16* h2s_hi = (u16*)alloc((size_t)B_ * TC_ * H_ * 2);   // chunk archive L2
  u16* h2s_lo = (u16*)alloc((size_t)B_ * TC_ * H_ * 2);
  float* xp   = (float*)alloc((size_t)B_ * TC_ * G4_ * 4); // 128 MB

  // ---- prep ----
  cvt_hilo<<<512, 256, 0, stream>>>(Wih1, Wih1_hi, Wih1_lo, G4_ * I_ / 4);
  cvt_hilo<<<512, 256, 0, stream>>>(Whh1, Whh1_hi, Whh1_lo, G4_ * H_ / 4);
  cvt_hilo<<<512, 256, 0, stream>>>(Wih2, Wih2_hi, Wih2_lo, G4_ * H_ / 4);
  cvt_hilo<<<512, 256, 0, stream>>>(Whh2, Whh2_hi, Whh2_lo, G4_ * H_ / 4);
  cvt_hilo<<<256, 256, 0, stream>>>(fcW,  fcW_hi,  fcW_lo,  O_ * H_ / 4);
  vadd<<<16, 256, 0, stream>>>(bih1, bhh1, bsum1, G4_);
  vadd<<<16, 256, 0, stream>>>(bih2, bhh2, bsum2, G4_);

  hipMemsetAsync(cst1,  0, (size_t)B_ * H_ * 4, stream);
  hipMemsetAsync(cst2,  0, (size_t)B_ * H_ * 4, stream);
  hipMemsetAsync(h1b0h, 0, (size_t)B_ * H_ * 2, stream);
  hipMemsetAsync(h1b0l, 0, (size_t)B_ * H_ * 2, stream);
  hipMemsetAsync(h2b0h, 0, (size_t)B_ * H_ * 2, stream);
  hipMemsetAsync(h2b0l, 0, (size_t)B_ * H_ * 2, stream);

  const dim3 gX(64 * TC_ / 64, G4_ / 64);   // (128, 64)
  const dim3 gF(64 * TC_ / 64, O_  / 64);   // (128, 8)

  for (int c = 0; c < NCH; ++c){
    int c0 = c * TC_;
    // xp1 = x @ Wih1^T + bsum1
    gemm3<I_, 0, false><<<gX, 256, 0, stream>>>(
        x, nullptr, nullptr, Wih1_hi, Wih1_lo, bsum1, xp, G4_, c0);
    // L1 recurrent chunk
    {
      void* args[] = { (void*)&Whh1_hi, (void*)&Whh1_lo, (void*)&xp, (void*)&cst1,
                       (void*)&h1b0h, (void*)&h1b0l, (void*)&h1b1h, (void*)&h1b1l,
                       (void*)&h1s_hi, (void*)&h1s_lo };
      hipLaunchCooperativeKernel((const void*)lstm_chunk, dim3(NWG), dim3(512),
                                 args, 0, stream);
    }
    // xp2 = h1s_chunk @ Wih2^T + bsum2
    gemm3<H_, 1, false><<<gX, 256, 0, stream>>>(
        nullptr, h1s_hi, h1s_lo, Wih2_hi, Wih2_lo, bsum2, xp, G4_, c0);
    // L2 recurrent chunk
    {
      void* args[] = { (void*)&Whh2_hi, (void*)&Whh2_lo, (void*)&xp, (void*)&cst2,
                       (void*)&h2b0h, (void*)&h2b0l, (void*)&h2b1h, (void*)&h2b1l,
                       (void*)&h2s_hi, (void*)&h2s_lo };
      hipLaunchCooperativeKernel((const void*)lstm_chunk, dim3(NWG), dim3(512),
                                 args, 0, stream);
    }
    // FC chunk -> out
    gemm3<H_, 1, true><<<gF, 256, 0, stream>>>(
        nullptr, h2s_hi, h2s_lo, fcW_hi, fcW_lo, fcb, out, O_, c0);
  }
}

// Round 3
// 23419.545 us; speedup vs baseline: 4.7534x; 4.7534x over previous
//
#include <hip/hip_runtime.h>
#include <hip/hip_bf16.h>
#include <math.h>

#define B_  64
#define T_  512
#define I_  512
#define H_  1024
#define G4_ 4096
#define O_  512
#define TC_ 128            // time chunk
#define NCH (T_ / TC_)     // 4

typedef short  s16x8 __attribute__((ext_vector_type(8)));
typedef float  fx4   __attribute__((ext_vector_type(4)));
typedef float  fx8   __attribute__((ext_vector_type(8)));
typedef unsigned short u16;
typedef u16    u16x4 __attribute__((ext_vector_type(4)));

__device__ __forceinline__ u16 f2bf(float f){
  unsigned u = __float_as_uint(f);
  unsigned r = u + 0x7fffu + ((u >> 16) & 1u);   // RNE
  return (u16)(r >> 16);
}
__device__ __forceinline__ float bf2f(u16 s){ return __uint_as_float(((unsigned)s) << 16); }
__device__ __forceinline__ float sigm(float x){ return 1.0f / (1.0f + __expf(-x)); }
__device__ __forceinline__ float tanh_(float x){
  float ax = fabsf(x);
  float e  = __expf(2.0f * ax);
  float r  = 1.0f - 2.0f / (e + 1.0f);
  return copysignf(r, x);
}
__device__ __forceinline__ fx4 mfma(s16x8 a, s16x8 b, fx4 c){
  return __builtin_amdgcn_mfma_f32_16x16x32_bf16(a, b, c, 0, 0, 0);
}

// ---------------- prep kernels ----------------
__global__ void cvt_hilo(const float* __restrict__ src, u16* __restrict__ hi,
                         u16* __restrict__ lo, int n4){
  int i      = blockIdx.x * blockDim.x + threadIdx.x;
  int stride = gridDim.x * blockDim.x;
  for (; i < n4; i += stride){
    fx4 v = ((const fx4*)src)[i];
    u16x4 h, l;
    #pragma unroll
    for (int k = 0; k < 4; ++k){
      u16 hh = f2bf(v[k]);
      h[k] = hh;
      l[k] = f2bf(v[k] - bf2f(hh));
    }
    ((u16x4*)hi)[i] = h;
    ((u16x4*)lo)[i] = l;
  }
}

__global__ void vadd(const float* __restrict__ a, const float* __restrict__ b,
                     float* __restrict__ o, int n){
  int i = blockIdx.x * blockDim.x + threadIdx.x;
  if (i < n) o[i] = a[i] + b[i];
}

// ---------------- GEMM (split-bf16, 64x64 tile, streaming) ----------------
// out[r, n] = sum_k A[r, k] * Bmat[n, k] + bias[n]; M = 64*TC_ rows, r=(b,tl).
// AMODE 0: A = fp32 x [b][c0+tl][KD]; AMODE 1: A = hi/lo pair [r][KD].
// OUT_BT false: out[r*N + n]; true: out[(b*T_+c0+tl)*N + n].
template<int KD, int AMODE, bool OUT_BT>
__global__ __launch_bounds__(256)
void gemm3(const float* __restrict__ Af,
           const u16* __restrict__ Ah, const u16* __restrict__ Al,
           const u16* __restrict__ Bh, const u16* __restrict__ Bl,
           const float* __restrict__ bias,
           float* __restrict__ out, int N, int c0)
{
  const int lane = threadIdx.x & 63;
  const int wv   = threadIdx.x >> 6;
  const int l15  = lane & 15;
  const int lhi  = lane >> 4;
  const int koff = lhi * 8;
  const int mb   = blockIdx.x * 64 + wv * 16;
  const int nb   = blockIdx.y * 64;
  const int arow = mb + l15;

  fx4 acc[4] = {};
  for (int kt = 0; kt < KD / 32; ++kt){
    const int kb = kt * 32 + koff;
    s16x8 ah, al;
    if (AMODE == 0){
      const int b  = arow / TC_;
      const int tl = arow % TC_;
      const float* p = Af + ((size_t)b * T_ + c0 + tl) * KD + kb;
      fx8 v = *reinterpret_cast<const fx8*>(p);
      #pragma unroll
      for (int i = 0; i < 8; ++i){
        u16 h = f2bf(v[i]);
        ah[i] = (short)h;
        al[i] = (short)f2bf(v[i] - bf2f(h));
      }
    } else {
      const size_t ao = (size_t)arow * KD + kb;
      ah = *reinterpret_cast<const s16x8*>(Ah + ao);
      al = *reinterpret_cast<const s16x8*>(Al + ao);
    }
    #pragma unroll
    for (int c = 0; c < 4; ++c){
      const size_t wo = (size_t)(nb + c * 16 + l15) * KD + kb;
      s16x8 bh = *reinterpret_cast<const s16x8*>(Bh + wo);
      s16x8 bl = *reinterpret_cast<const s16x8*>(Bl + wo);
      acc[c] = mfma(ah, bh, acc[c]);
      acc[c] = mfma(ah, bl, acc[c]);
      acc[c] = mfma(al, bh, acc[c]);
    }
  }
  #pragma unroll
  for (int c = 0; c < 4; ++c){
    const int n = nb + c * 16 + l15;
    const float bv = bias[n];
    #pragma unroll
    for (int r = 0; r < 4; ++r){
      const int m = mb + lhi * 4 + r;
      float v = acc[c][r] + bv;
      if (OUT_BT){
        const int b  = m / TC_;
        const int tl = m % TC_;
        out[((size_t)b * T_ + c0 + tl) * (size_t)N + n] = v;
      } else {
        out[(size_t)m * (size_t)N + n] = v;
      }
    }
  }
}

// ---------------- per-timestep LSTM kernel (full-width) ----------------
// 256 WGs x 512 threads. WG owns 4 hidden units (16 gate-cols: c=l15 -> gate c>>2,
// unit c&3). 8 waves K-split K=1024 into 128 each; LDS reduce; wave-local update.
__global__ __launch_bounds__(512)
void lstm_step2(const u16* __restrict__ Whh_hi, const u16* __restrict__ Whh_lo, // [4096,1024]
                const float* __restrict__ xp,   // [B][TC_][4096] fp32 (bias included)
                float* __restrict__ cst,        // [H][B]: j*B_ + m
                const u16* __restrict__ rh, const u16* __restrict__ rl, // read h [B][H]
                u16* __restrict__ nh, u16* __restrict__ nl,             // write h [B][H]
                u16* __restrict__ hah, u16* __restrict__ hal,           // archive [B][TC_][H]
                int tl)
{
  __shared__ float red[64 * 129];           // [m][c*8+w], stride 129: reads conflict-free

  const int tid  = threadIdx.x;
  const int lane = tid & 63;
  const int wv   = tid >> 6;                // 0..7
  const int l15  = lane & 15;
  const int lhi  = lane >> 4;
  const int koff = lhi * 8;
  const int jb4  = blockIdx.x * 4;
  const int wrow = (l15 >> 2) * H_ + jb4 + (l15 & 3);

  // prefetch xp + c (epilogue data) so HBM latency hides under the GEMM
  const int em = tid & 63;
  const int eu = tid >> 6;
  float xpv0 = 0, xpv1 = 0, xpv2 = 0, xpv3 = 0, cv = 0;
  if (tid < 256){
    const int ej = jb4 + eu;
    const float* xr = xp + ((size_t)em * TC_ + tl) * G4_ + ej;
    xpv0 = xr[0]; xpv1 = xr[H_]; xpv2 = xr[2 * H_]; xpv3 = xr[3 * H_];
    cv = cst[ej * B_ + em];
  }

  fx4 acc[4] = {};
  const int kb0 = wv * 128 + koff;
  #pragma unroll
  for (int s = 0; s < 4; ++s){
    const int kb = kb0 + s * 32;
    const size_t wo = (size_t)wrow * H_ + kb;
    s16x8 bh = *reinterpret_cast<const s16x8*>(Whh_hi + wo);
    s16x8 bl = *reinterpret_cast<const s16x8*>(Whh_lo + wo);
    #pragma unroll
    for (int mt = 0; mt < 4; ++mt){
      const size_t ho = (size_t)(mt * 16 + l15) * H_ + kb;
      s16x8 ah = *reinterpret_cast<const s16x8*>(rh + ho);
      s16x8 al = *reinterpret_cast<const s16x8*>(rl + ho);
      acc[mt] = mfma(ah, bh, acc[mt]);
      acc[mt] = mfma(ah, bl, acc[mt]);
      acc[mt] = mfma(al, bh, acc[mt]);
    }
  }

  // partials -> LDS. D layout: col c = l15, row m = mt*16 + lhi*4 + r
  #pragma unroll
  for (int mt = 0; mt < 4; ++mt)
    #pragma unroll
    for (int r = 0; r < 4; ++r)
      red[(mt * 16 + lhi * 4 + r) * 129 + l15 * 8 + wv] = acc[mt][r];
  __syncthreads();

  if (tid < 256){
    const int ej = jb4 + eu;
    float g[4];
    #pragma unroll
    for (int gi = 0; gi < 4; ++gi){
      const float* rp = red + em * 129 + (gi * 4 + eu) * 8;
      g[gi] = ((rp[0] + rp[1]) + (rp[2] + rp[3])) + ((rp[4] + rp[5]) + (rp[6] + rp[7]));
    }
    float iv = sigm (g[0] + xpv0);
    float fv = sigm (g[1] + xpv1);
    float gv = tanh_(g[2] + xpv2);
    float ov = sigm (g[3] + xpv3);
    float cn = fv * cv + iv * gv;
    float hv = ov * tanh_(cn);
    cst[ej * B_ + em] = cn;
    u16 hh = f2bf(hv);
    u16 hl = f2bf(hv - bf2f(hh));
    nh[em * H_ + ej] = hh;
    nl[em * H_ + ej] = hl;
    const size_t ai = ((size_t)em * TC_ + tl) * H_ + ej;
    hah[ai] = hh;
    hal[ai] = hl;
  }
}

// ---------------- host launch ----------------
extern "C" void kernel_launch(void* const* d_in, const int* in_sizes, int n_in,
                              void* d_out, int out_size, void* d_ws, size_t ws_size,
                              hipStream_t stream)
{
  const float* x    = (const float*)d_in[0];
  const float* Wih1 = (const float*)d_in[1];
  const float* Whh1 = (const float*)d_in[2];
  const float* bih1 = (const float*)d_in[3];
  const float* bhh1 = (const float*)d_in[4];
  const float* Wih2 = (const float*)d_in[5];
  const float* Whh2 = (const float*)d_in[6];
  const float* bih2 = (const float*)d_in[7];
  const float* bhh2 = (const float*)d_in[8];
  const float* fcW  = (const float*)d_in[9];
  const float* fcb  = (const float*)d_in[10];
  float* out = (float*)d_out;
  (void)in_sizes; (void)n_in; (void)out_size; (void)ws_size;

  char* base = (char*)d_ws;
  size_t off = 0;
  auto alloc = [&](size_t bytes) -> void* {
    void* p = base + off;
    off = (off + bytes + 255) & ~(size_t)255;
    return p;
  };
  u16* Wih1_hi = (u16*)alloc((size_t)G4_ * I_ * 2);
  u16* Wih1_lo = (u16*)alloc((size_t)G4_ * I_ * 2);
  u16* Whh1_hi = (u16*)alloc((size_t)G4_ * H_ * 2);
  u16* Whh1_lo = (u16*)alloc((size_t)G4_ * H_ * 2);
  u16* Wih2_hi = (u16*)alloc((size_t)G4_ * H_ * 2);
  u16* Wih2_lo = (u16*)alloc((size_t)G4_ * H_ * 2);
  u16* Whh2_hi = (u16*)alloc((size_t)G4_ * H_ * 2);
  u16* Whh2_lo = (u16*)alloc((size_t)G4_ * H_ * 2);
  u16* fcW_hi  = (u16*)alloc((size_t)O_ * H_ * 2);
  u16* fcW_lo  = (u16*)alloc((size_t)O_ * H_ * 2);
  float* bsum1 = (float*)alloc((size_t)G4_ * 4);
  float* bsum2 = (float*)alloc((size_t)G4_ * 4);
  float* cst1  = (float*)alloc((size_t)B_ * H_ * 4);
  float* cst2  = (float*)alloc((size_t)B_ * H_ * 4);
  u16* h1b0h = (u16*)alloc((size_t)B_ * H_ * 2);
  u16* h1b0l = (u16*)alloc((size_t)B_ * H_ * 2);
  u16* h1b1h = (u16*)alloc((size_t)B_ * H_ * 2);
  u16* h1b1l = (u16*)alloc((size_t)B_ * H_ * 2);
  u16* h2b0h = (u16*)alloc((size_t)B_ * H_ * 2);
  u16* h2b0l = (u16*)alloc((size_t)B_ * H_ * 2);
  u16* h2b1h = (u16*)alloc((size_t)B_ * H_ * 2);
  u16* h2b1l = (u16*)alloc((size_t)B_ * H_ * 2);
  u16* h1s_hi = (u16*)alloc((size_t)B_ * TC_ * H_ * 2);
  u16* h1s_lo = (u16*)alloc((size_t)B_ * TC_ * H_ * 2);
  u16* h2s_hi = (u16*)alloc((size_t)B_ * TC_ * H_ * 2);
  u16* h2s_lo = (u16*)alloc((size_t)B_ * TC_ * H_ * 2);
  float* xp   = (float*)alloc((size_t)B_ * TC_ * G4_ * 4); // 128 MB

  u16* h1h[2] = { h1b0h, h1b1h };
  u16* h1l[2] = { h1b0l, h1b1l };
  u16* h2h[2] = { h2b0h, h2b1h };
  u16* h2l[2] = { h2b0l, h2b1l };

  // ---- prep ----
  cvt_hilo<<<512, 256, 0, stream>>>(Wih1, Wih1_hi, Wih1_lo, G4_ * I_ / 4);
  cvt_hilo<<<512, 256, 0, stream>>>(Whh1, Whh1_hi, Whh1_lo, G4_ * H_ / 4);
  cvt_hilo<<<512, 256, 0, stream>>>(Wih2, Wih2_hi, Wih2_lo, G4_ * H_ / 4);
  cvt_hilo<<<512, 256, 0, stream>>>(Whh2, Whh2_hi, Whh2_lo, G4_ * H_ / 4);
  cvt_hilo<<<256, 256, 0, stream>>>(fcW,  fcW_hi,  fcW_lo,  O_ * H_ / 4);
  vadd<<<16, 256, 0, stream>>>(bih1, bhh1, bsum1, G4_);
  vadd<<<16, 256, 0, stream>>>(bih2, bhh2, bsum2, G4_);

  hipMemsetAsync(cst1,  0, (size_t)B_ * H_ * 4, stream);
  hipMemsetAsync(cst2,  0, (size_t)B_ * H_ * 4, stream);
  hipMemsetAsync(h1b0h, 0, (size_t)B_ * H_ * 2, stream);
  hipMemsetAsync(h1b0l, 0, (size_t)B_ * H_ * 2, stream);
  hipMemsetAsync(h2b0h, 0, (size_t)B_ * H_ * 2, stream);
  hipMemsetAsync(h2b0l, 0, (size_t)B_ * H_ * 2, stream);

  const dim3 gX(64 * TC_ / 64, G4_ / 64);   // (128, 64)
  const dim3 gF(64 * TC_ / 64, O_  / 64);   // (128, 8)

  for (int c = 0; c < NCH; ++c){
    const int c0 = c * TC_;
    // xp1 = x @ Wih1^T + bsum1
    gemm3<I_, 0, false><<<gX, 256, 0, stream>>>(
        x, nullptr, nullptr, Wih1_hi, Wih1_lo, bsum1, xp, G4_, c0);
    // L1 recurrent steps
    for (int tl = 0; tl < TC_; ++tl){
      const int t = c0 + tl;
      lstm_step2<<<256, 512, 0, stream>>>(
          Whh1_hi, Whh1_lo, xp, cst1,
          h1h[t & 1], h1l[t & 1], h1h[(t + 1) & 1], h1l[(t + 1) & 1],
          h1s_hi, h1s_lo, tl);
    }
    // xp2 = h1s_chunk @ Wih2^T + bsum2
    gemm3<H_, 1, false><<<gX, 256, 0, stream>>>(
        nullptr, h1s_hi, h1s_lo, Wih2_hi, Wih2_lo, bsum2, xp, G4_, c0);
    // L2 recurrent steps
    for (int tl = 0; tl < TC_; ++tl){
      const int t = c0 + tl;
      lstm_step2<<<256, 512, 0, stream>>>(
          Whh2_hi, Whh2_lo, xp, cst2,
          h2h[t & 1], h2l[t & 1], h2h[(t + 1) & 1], h2l[(t + 1) & 1],
          h2s_hi, h2s_lo, tl);
    }
    // FC chunk -> out
    gemm3<H_, 1, true><<<gF, 256, 0, stream>>>(
        nullptr, h2s_hi, h2s_lo, fcW_hi, fcW_lo, fcb, out, O_, c0);
  }
}

// Round 4
// 17390.842 us; speedup vs baseline: 6.4012x; 1.3467x over previous
//
#include <hip/hip_runtime.h>
#include <hip/hip_bf16.h>
#include <math.h>

#define B_  64
#define T_  512
#define I_  512
#define H_  1024
#define G4_ 4096
#define O_  512
#define TC_ 64             // time chunk
#define NCH (T_ / TC_)     // 8

typedef short  s16x8 __attribute__((ext_vector_type(8)));
typedef float  fx4   __attribute__((ext_vector_type(4)));
typedef float  fx8   __attribute__((ext_vector_type(8)));
typedef unsigned short u16;
typedef u16    u16x4 __attribute__((ext_vector_type(4)));

__device__ __forceinline__ u16 f2bf(float f){
  unsigned u = __float_as_uint(f);
  unsigned r = u + 0x7fffu + ((u >> 16) & 1u);   // RNE
  return (u16)(r >> 16);
}
__device__ __forceinline__ float bf2f(u16 s){ return __uint_as_float(((unsigned)s) << 16); }
__device__ __forceinline__ float sigm(float x){ return 1.0f / (1.0f + __expf(-x)); }
__device__ __forceinline__ float tanh_(float x){
  float ax = fabsf(x);
  float e  = __expf(2.0f * ax);
  float r  = 1.0f - 2.0f / (e + 1.0f);
  return copysignf(r, x);
}
__device__ __forceinline__ fx4 mfma(s16x8 a, s16x8 b, fx4 c){
  return __builtin_amdgcn_mfma_f32_16x16x32_bf16(a, b, c, 0, 0, 0);
}

// ---------------- prep kernels ----------------
__global__ void cvt_hilo(const float* __restrict__ src, u16* __restrict__ hi,
                         u16* __restrict__ lo, int n4){
  int i      = blockIdx.x * blockDim.x + threadIdx.x;
  int stride = gridDim.x * blockDim.x;
  for (; i < n4; i += stride){
    fx4 v = ((const fx4*)src)[i];
    u16x4 h, l;
    #pragma unroll
    for (int k = 0; k < 4; ++k){
      u16 hh = f2bf(v[k]);
      h[k] = hh;
      l[k] = f2bf(v[k] - bf2f(hh));
    }
    ((u16x4*)hi)[i] = h;
    ((u16x4*)lo)[i] = l;
  }
}

__global__ void vadd(const float* __restrict__ a, const float* __restrict__ b,
                     float* __restrict__ o, int n){
  int i = blockIdx.x * blockDim.x + threadIdx.x;
  if (i < n) o[i] = a[i] + b[i];
}

// ---------------- bulk GEMM (split-bf16, 128x64 tile) ----------------
// Row index r = tl*64 + b (tl-major). out[r,n] = sum_k A[r,k]*Bmat[n,k] + bias[n].
// AMODE 0: A = fp32 x at [b][c0+tl][KD];  AMODE 1: A = hi/lo bf16 at [b*TC_+tl][KD].
// OMODE 0: xp layout out[((tl*4+g)*H + j)*64 + b]  (LDS-transposed, coalesced)
// OMODE 1: FC     out[(b*T_ + c0+tl)*N + n]
template<int KD, int AMODE, int OMODE>
__global__ __launch_bounds__(256)
void gemmX(const float* __restrict__ Af,
           const u16* __restrict__ Ah, const u16* __restrict__ Al,
           const u16* __restrict__ Bh, const u16* __restrict__ Bl,
           const float* __restrict__ bias,
           float* __restrict__ out, int N, int c0)
{
  __shared__ float xt[(OMODE == 0) ? 64 * 130 : 4];
  const int lane = threadIdx.x & 63;
  const int wv   = threadIdx.x >> 6;
  const int l15  = lane & 15;
  const int lhi  = lane >> 4;
  const int koff = lhi * 8;
  const int mb   = blockIdx.x * 128;
  const int nb   = blockIdx.y * 64;
  const int r0   = mb + wv * 32 + l15;

  fx4 acc[2][4] = {};
  for (int kt = 0; kt < KD / 32; ++kt){
    const int kb = kt * 32 + koff;
    s16x8 ah[2], al[2];
    #pragma unroll
    for (int mi = 0; mi < 2; ++mi){
      const int r  = r0 + mi * 16;
      const int b  = r & 63;
      const int tl = r >> 6;
      if (AMODE == 0){
        const float* p = Af + ((size_t)b * T_ + c0 + tl) * KD + kb;
        fx8 v = *reinterpret_cast<const fx8*>(p);
        #pragma unroll
        for (int i = 0; i < 8; ++i){
          u16 h = f2bf(v[i]);
          ah[mi][i] = (short)h;
          al[mi][i] = (short)f2bf(v[i] - bf2f(h));
        }
      } else {
        const size_t ao = ((size_t)b * TC_ + tl) * KD + kb;
        ah[mi] = *reinterpret_cast<const s16x8*>(Ah + ao);
        al[mi] = *reinterpret_cast<const s16x8*>(Al + ao);
      }
    }
    #pragma unroll
    for (int c = 0; c < 4; ++c){
      const size_t wo = (size_t)(nb + c * 16 + l15) * KD + kb;
      s16x8 bh = *reinterpret_cast<const s16x8*>(Bh + wo);
      s16x8 bl = *reinterpret_cast<const s16x8*>(Bl + wo);
      #pragma unroll
      for (int mi = 0; mi < 2; ++mi){
        acc[mi][c] = mfma(ah[mi], bh, acc[mi][c]);
        acc[mi][c] = mfma(ah[mi], bl, acc[mi][c]);
        acc[mi][c] = mfma(al[mi], bh, acc[mi][c]);
      }
    }
  }

  if (OMODE == 0){
    #pragma unroll
    for (int c = 0; c < 4; ++c){
      const int nloc = c * 16 + l15;
      const float bv = bias[nb + nloc];
      #pragma unroll
      for (int mi = 0; mi < 2; ++mi)
        #pragma unroll
        for (int r = 0; r < 4; ++r)
          xt[nloc * 130 + wv * 32 + mi * 16 + lhi * 4 + r] = acc[mi][c][r] + bv;
    }
    __syncthreads();
    const int mloc = threadIdx.x & 127;
    const int b    = mloc & 63;
    const int tl   = blockIdx.x * 2 + (mloc >> 6);
    #pragma unroll
    for (int it = 0; it < 32; ++it){
      const int nloc = (threadIdx.x >> 7) + it * 2;
      const int n = nb + nloc;
      const int g = n >> 10;
      const int j = n & 1023;
      out[((size_t)(tl * 4 + g) * H_ + j) * 64 + b] = xt[nloc * 130 + mloc];
    }
  } else {
    #pragma unroll
    for (int c = 0; c < 4; ++c){
      const int n = nb + c * 16 + l15;
      const float bv = bias[n];
      #pragma unroll
      for (int mi = 0; mi < 2; ++mi)
        #pragma unroll
        for (int r = 0; r < 4; ++r){
          const int m  = mb + wv * 32 + mi * 16 + lhi * 4 + r;
          const int b  = m & 63;
          const int tl = m >> 6;
          out[((size_t)b * T_ + c0 + tl) * (size_t)N + n] = acc[mi][c][r] + bv;
        }
    }
  }
}

// ---------------- dual-layer pipelined LSTM step ----------------
// mode bit0: L1 active, bit1: L2 active. When mode==3, grid=512: blocks 0-255=L1,
// 256-511=L2. WG owns 4 hidden units (16 gate-cols). 8 waves K-split K=1024.
__global__ __launch_bounds__(512)
void lstm_step_dual(int mode, int tl,
    const u16* __restrict__ W1h, const u16* __restrict__ W1l,
    const float* __restrict__ xp1, float* __restrict__ cst1,
    const u16* __restrict__ rh1, const u16* __restrict__ rl1,
    u16* __restrict__ nh1, u16* __restrict__ nl1,
    u16* __restrict__ ha1h, u16* __restrict__ ha1l,
    const u16* __restrict__ W2h, const u16* __restrict__ W2l,
    const float* __restrict__ xp2, float* __restrict__ cst2,
    const u16* __restrict__ rh2, const u16* __restrict__ rl2,
    u16* __restrict__ nh2, u16* __restrict__ nl2,
    u16* __restrict__ ha2h, u16* __restrict__ ha2l)
{
  __shared__ float red[64 * 129];

  int part, bx;
  if (mode == 3){ part = blockIdx.x >> 8; bx = blockIdx.x & 255; }
  else          { part = mode - 1;        bx = blockIdx.x; }

  const u16*   Wh  = part ? W2h  : W1h;
  const u16*   Wl  = part ? W2l  : W1l;
  const float* xp  = part ? xp2  : xp1;
  float*       cst = part ? cst2 : cst1;
  const u16*   rh  = part ? rh2  : rh1;
  const u16*   rl  = part ? rl2  : rl1;
  u16*         nh  = part ? nh2  : nh1;
  u16*         nl  = part ? nl2  : nl1;
  u16*         hah = part ? ha2h : ha1h;
  u16*         hal = part ? ha2l : ha1l;

  const int tid  = threadIdx.x;
  const int lane = tid & 63;
  const int wv   = tid >> 6;
  const int l15  = lane & 15;
  const int lhi  = lane >> 4;
  const int koff = lhi * 8;
  const int jb4  = bx * 4;
  const int wrow = (l15 >> 2) * H_ + jb4 + (l15 & 3);

  // prefetch epilogue data (coalesced: b innermost)
  const int em = tid & 63;
  const int eu = tid >> 6;
  float xpv0 = 0, xpv1 = 0, xpv2 = 0, xpv3 = 0, cv = 0;
  if (tid < 256){
    const int ej = jb4 + eu;
    const float* xr = xp + ((size_t)(tl * 4) * H_ + ej) * 64 + em;
    xpv0 = xr[0];
    xpv1 = xr[(size_t)H_ * 64];
    xpv2 = xr[(size_t)2 * H_ * 64];
    xpv3 = xr[(size_t)3 * H_ * 64];
    cv = cst[ej * B_ + em];
  }

  fx4 acc[4] = {};
  const int kb0 = wv * 128 + koff;
  #pragma unroll
  for (int s = 0; s < 4; ++s){
    const int kb = kb0 + s * 32;
    const size_t wo = (size_t)wrow * H_ + kb;
    s16x8 bh = *reinterpret_cast<const s16x8*>(Wh + wo);
    s16x8 bl = *reinterpret_cast<const s16x8*>(Wl + wo);
    #pragma unroll
    for (int mt = 0; mt < 4; ++mt){
      const size_t ho = (size_t)(mt * 16 + l15) * H_ + kb;
      s16x8 ah = *reinterpret_cast<const s16x8*>(rh + ho);
      s16x8 al = *reinterpret_cast<const s16x8*>(rl + ho);
      acc[mt] = mfma(ah, bh, acc[mt]);
      acc[mt] = mfma(ah, bl, acc[mt]);
      acc[mt] = mfma(al, bh, acc[mt]);
    }
  }

  #pragma unroll
  for (int mt = 0; mt < 4; ++mt)
    #pragma unroll
    for (int r = 0; r < 4; ++r)
      red[(mt * 16 + lhi * 4 + r) * 129 + l15 * 8 + wv] = acc[mt][r];
  __syncthreads();

  if (tid < 256){
    const int ej = jb4 + eu;
    float g[4];
    #pragma unroll
    for (int gi = 0; gi < 4; ++gi){
      const float* rp = red + em * 129 + (gi * 4 + eu) * 8;
      g[gi] = ((rp[0] + rp[1]) + (rp[2] + rp[3])) + ((rp[4] + rp[5]) + (rp[6] + rp[7]));
    }
    float iv = sigm (g[0] + xpv0);
    float fv = sigm (g[1] + xpv1);
    float gv = tanh_(g[2] + xpv2);
    float ov = sigm (g[3] + xpv3);
    float cn = fv * cv + iv * gv;
    float hv = ov * tanh_(cn);
    cst[ej * B_ + em] = cn;
    u16 hh = f2bf(hv);
    u16 hl = f2bf(hv - bf2f(hh));
    nh[em * H_ + ej] = hh;
    nl[em * H_ + ej] = hl;
    const size_t ai = ((size_t)em * TC_ + tl) * H_ + ej;
    hah[ai] = hh;
    hal[ai] = hl;
  }
}

// ---------------- host launch ----------------
extern "C" void kernel_launch(void* const* d_in, const int* in_sizes, int n_in,
                              void* d_out, int out_size, void* d_ws, size_t ws_size,
                              hipStream_t stream)
{
  const float* x    = (const float*)d_in[0];
  const float* Wih1 = (const float*)d_in[1];
  const float* Whh1 = (const float*)d_in[2];
  const float* bih1 = (const float*)d_in[3];
  const float* bhh1 = (const float*)d_in[4];
  const float* Wih2 = (const float*)d_in[5];
  const float* Whh2 = (const float*)d_in[6];
  const float* bih2 = (const float*)d_in[7];
  const float* bhh2 = (const float*)d_in[8];
  const float* fcW  = (const float*)d_in[9];
  const float* fcb  = (const float*)d_in[10];
  float* out = (float*)d_out;
  (void)in_sizes; (void)n_in; (void)out_size; (void)ws_size;

  char* base = (char*)d_ws;
  size_t off = 0;
  auto alloc = [&](size_t bytes) -> void* {
    void* p = base + off;
    off = (off + bytes + 255) & ~(size_t)255;
    return p;
  };
  u16* Wih1_hi = (u16*)alloc((size_t)G4_ * I_ * 2);
  u16* Wih1_lo = (u16*)alloc((size_t)G4_ * I_ * 2);
  u16* Whh1_hi = (u16*)alloc((size_t)G4_ * H_ * 2);
  u16* Whh1_lo = (u16*)alloc((size_t)G4_ * H_ * 2);
  u16* Wih2_hi = (u16*)alloc((size_t)G4_ * H_ * 2);
  u16* Wih2_lo = (u16*)alloc((size_t)G4_ * H_ * 2);
  u16* Whh2_hi = (u16*)alloc((size_t)G4_ * H_ * 2);
  u16* Whh2_lo = (u16*)alloc((size_t)G4_ * H_ * 2);
  u16* fcW_hi  = (u16*)alloc((size_t)O_ * H_ * 2);
  u16* fcW_lo  = (u16*)alloc((size_t)O_ * H_ * 2);
  float* bsum1 = (float*)alloc((size_t)G4_ * 4);
  float* bsum2 = (float*)alloc((size_t)G4_ * 4);
  float* cst1  = (float*)alloc((size_t)B_ * H_ * 4);
  float* cst2  = (float*)alloc((size_t)B_ * H_ * 4);
  u16* h1b0h = (u16*)alloc((size_t)B_ * H_ * 2);
  u16* h1b0l = (u16*)alloc((size_t)B_ * H_ * 2);
  u16* h1b1h = (u16*)alloc((size_t)B_ * H_ * 2);
  u16* h1b1l = (u16*)alloc((size_t)B_ * H_ * 2);
  u16* h2b0h = (u16*)alloc((size_t)B_ * H_ * 2);
  u16* h2b0l = (u16*)alloc((size_t)B_ * H_ * 2);
  u16* h2b1h = (u16*)alloc((size_t)B_ * H_ * 2);
  u16* h2b1l = (u16*)alloc((size_t)B_ * H_ * 2);
  u16* h1s_hi = (u16*)alloc((size_t)B_ * TC_ * H_ * 2);
  u16* h1s_lo = (u16*)alloc((size_t)B_ * TC_ * H_ * 2);
  u16* h2s_hi = (u16*)alloc((size_t)B_ * TC_ * H_ * 2);
  u16* h2s_lo = (u16*)alloc((size_t)B_ * TC_ * H_ * 2);
  float* xp1  = (float*)alloc((size_t)TC_ * G4_ * B_ * 4);  // 64 MB, [tl][g][j][b]
  float* xp2  = (float*)alloc((size_t)TC_ * G4_ * B_ * 4);  // 64 MB

  u16* h1h[2] = { h1b0h, h1b1h };
  u16* h1l[2] = { h1b0l, h1b1l };
  u16* h2h[2] = { h2b0h, h2b1h };
  u16* h2l[2] = { h2b0l, h2b1l };

  // ---- prep ----
  cvt_hilo<<<512, 256, 0, stream>>>(Wih1, Wih1_hi, Wih1_lo, G4_ * I_ / 4);
  cvt_hilo<<<512, 256, 0, stream>>>(Whh1, Whh1_hi, Whh1_lo, G4_ * H_ / 4);
  cvt_hilo<<<512, 256, 0, stream>>>(Wih2, Wih2_hi, Wih2_lo, G4_ * H_ / 4);
  cvt_hilo<<<512, 256, 0, stream>>>(Whh2, Whh2_hi, Whh2_lo, G4_ * H_ / 4);
  cvt_hilo<<<256, 256, 0, stream>>>(fcW,  fcW_hi,  fcW_lo,  O_ * H_ / 4);
  vadd<<<16, 256, 0, stream>>>(bih1, bhh1, bsum1, G4_);
  vadd<<<16, 256, 0, stream>>>(bih2, bhh2, bsum2, G4_);

  hipMemsetAsync(cst1,  0, (size_t)B_ * H_ * 4, stream);
  hipMemsetAsync(cst2,  0, (size_t)B_ * H_ * 4, stream);
  hipMemsetAsync(h1b0h, 0, (size_t)B_ * H_ * 2, stream);
  hipMemsetAsync(h1b0l, 0, (size_t)B_ * H_ * 2, stream);
  hipMemsetAsync(h2b0h, 0, (size_t)B_ * H_ * 2, stream);
  hipMemsetAsync(h2b0l, 0, (size_t)B_ * H_ * 2, stream);

  const dim3 gX(32, 64);   // M=4096/128, N=4096/64
  const dim3 gF(32, 8);    // M=4096/128, N=512/64

  // xp1 for chunk 0
  gemmX<I_, 0, 0><<<gX, 256, 0, stream>>>(
      x, nullptr, nullptr, Wih1_hi, Wih1_lo, bsum1, xp1, G4_, 0);

  for (int c = 0; c <= NCH; ++c){
    const int mode = ((c < NCH) ? 1 : 0) | ((c >= 1) ? 2 : 0);
    const int nwg  = (mode == 3) ? 512 : 256;
    for (int tl = 0; tl < TC_; ++tl){
      const int par = tl & 1;
      lstm_step_dual<<<nwg, 512, 0, stream>>>(mode, tl,
          Whh1_hi, Whh1_lo, xp1, cst1,
          h1h[par], h1l[par], h1h[par ^ 1], h1l[par ^ 1], h1s_hi, h1s_lo,
          Whh2_hi, Whh2_lo, xp2, cst2,
          h2h[par], h2l[par], h2h[par ^ 1], h2l[par ^ 1], h2s_hi, h2s_lo);
    }
    if (c < NCH)
      gemmX<H_, 1, 0><<<gX, 256, 0, stream>>>(
          nullptr, h1s_hi, h1s_lo, Wih2_hi, Wih2_lo, bsum2, xp2, G4_, 0);
    if (c + 1 < NCH)
      gemmX<I_, 0, 0><<<gX, 256, 0, stream>>>(
          x, nullptr, nullptr, Wih1_hi, Wih1_lo, bsum1, xp1, G4_, (c + 1) * TC_);
    if (c >= 1)
      gemmX<H_, 1, 1><<<gF, 256, 0, stream>>>(
          nullptr, h2s_hi, h2s_lo, fcW_hi, fcW_lo, fcb, out, O_, (c - 1) * TC_);
  }
}